// Round 18
// baseline (249.720 us; speedup 1.0000x reference)
//
#include <hip/hip_runtime.h>
#include <hip/hip_cooperative_groups.h>

namespace cg = cooperative_groups;

// ROI point pooling via fixed-capacity spatial buckets — ONE cooperative
// dispatch, 256-thread blocks (R17's 512-thread variant exceeded the
// cooperative co-residency VGPR budget and the launch silently failed;
// 256 thr x 1024 blocks = 4 blocks/CU = 16 waves/CU -> 128-VGPR budget,
// 2x headroom). Launch return code checked; on any failure falls back to
// the proven R15 3-dispatch stream pipeline.
//
// P0: bincnt[128*128] = 0.                            (grid.sync)
// P1: scatter: one point/thread (262144 >= N): slot=atomicAdd(bincnt[bin]);
//     bucket[bin][slot]=(x,y,z,idx).                  (grid.sync)
// P2: block = anchor: stage exact-window bin counts in LDS; flat scan
//     bins x 32 slots guarded by staged count; hits set bit idx in a
//     3584-word LDS bitmask (atomicOr, idempotent). Rank = popcount
//     block-scan (14 words/thread, wave shfl-scan + 4-wave combine); each
//     thread emits its own bits to consecutive slots: slot k =
//     #(set bits < idx) == reference cumsum order. Tail zeroed (absorbs
//     the output clear; d_out is 0xAA-poisoned). counts[a]=min(total,n).
//
// Capacity: lambda=6.1 pts/bin -> CAPB=32 ~ 10 sigma (no drops).
// Bitmask covers N <= 3584*32 = 114688 (N=100000).

#define NB     128
#define NBB    (NB * NB)
#define CAPB   32
#define NWRD   3584
#define WPT    14           // 14 words x 256 threads = 3584
#define MAXBIN 160          // window bins <= 12x12 = 144

__global__ __launch_bounds__(256) void fused_kernel(
    const float* __restrict__ pts, const float* __restrict__ anc,
    int* __restrict__ bincnt, float4* __restrict__ bucket,
    float* __restrict__ out_pts, float* __restrict__ out_cnt,
    int N, int n, int A)
{
    const int tid  = threadIdx.x;
    const int gt   = blockIdx.x * 256 + tid;
    const int lane = tid & 63;
    const int wave = tid >> 6;

    // ---- P0: zero bin counters ----
    if (gt < NBB) bincnt[gt] = 0;
    cg::this_grid().sync();

    // ---- P1: scatter points into buckets (262144 threads >= N) ----
    if (gt < N) {
        const float px = pts[3 * gt + 0], py = pts[3 * gt + 1], pz = pts[3 * gt + 2];
        const float s = NB / 100.0f;
        const int bx = min(NB - 1, (int)(px * s));   // px,py >= 0
        const int by = min(NB - 1, (int)(py * s));
        const int bin = by * NB + bx;
        const int slot = atomicAdd(&bincnt[bin], 1);
        if (slot < CAPB)
            bucket[bin * CAPB + slot] = make_float4(px, py, pz, __int_as_float(gt));
    }
    cg::this_grid().sync();

    // ---- P2: per-anchor pooling (block = anchor) ----
    const int a = blockIdx.x;
    if (a >= A) return;

    const float cx = anc[a * 6 + 0], cy = anc[a * 6 + 1];
    const float w  = anc[a * 6 + 3], l  = anc[a * 6 + 4], h = anc[a * 6 + 5];
    const float xl = cx - w * 0.5f, xh = cx + w * 0.5f;
    const float yl = cy - l * 0.5f, yh = cy + l * 0.5f;

    __shared__ unsigned int s_mask[NWRD];
    __shared__ int s_bcnt[MAXBIN];
    __shared__ int s_wsum[4], s_wpre[5];

    #pragma unroll
    for (int u = 0; u < WPT; ++u) s_mask[tid + u * 256] = 0u;  // coalesced clear

    const float sc = NB / 100.0f;
    const int bx0 = max(0, (int)floorf(xl * sc));
    const int bx1 = min(NB - 1, (int)floorf(xh * sc));
    const int by0 = max(0, (int)floorf(yl * sc));
    const int by1 = min(NB - 1, (int)floorf(yh * sc));
    const int nbx = bx1 - bx0 + 1;               // <= 12
    const int nby = by1 - by0 + 1;               // <= 12
    const int nbins = (nbx > 0 && nby > 0) ? nbx * nby : 0;

    for (int t = tid; t < nbins; t += 256) {     // stage window bin counts
        const int by = by0 + t / nbx, bx = bx0 + t % nbx;
        s_bcnt[t] = min(bincnt[by * NB + bx], CAPB);
    }
    __syncthreads();

    const int tot = nbins << 5;                  // bins x 32 slots
    for (int t = tid; t < tot; t += 256) {
        const int slot = t & (CAPB - 1);
        const int b    = t >> 5;
        if (slot < s_bcnt[b]) {
            const int bin  = (by0 + b / nbx) * NB + bx0 + b % nbx;
            const float4 p = bucket[bin * CAPB + slot];
            if (p.x >= xl && p.x <= xh && p.y >= yl && p.y <= yh &&
                p.z >= 0.0f && p.z <= h) {
                const int idx = __float_as_int(p.w);
                atomicOr(&s_mask[idx >> 5], 1u << (idx & 31));
            }
        }
    }
    __syncthreads();

    // Popcount block-scan: thread owns words [tid*14, tid*14+14).
    const int wbase = tid * WPT;
    int s = 0;
    unsigned int mw[WPT];
    #pragma unroll
    for (int u = 0; u < WPT; ++u) {              // stride-14: 4-way max, cheap
        mw[u] = s_mask[wbase + u];
        s += __popc(mw[u]);
    }
    int incl = s;
    #pragma unroll
    for (int d = 1; d < 64; d <<= 1) {
        const int t = __shfl_up(incl, d);
        if (lane >= d) incl += t;
    }
    if (lane == 63) s_wsum[wave] = incl;
    __syncthreads();
    if (tid == 0) {
        int run = 0;
        #pragma unroll
        for (int v = 0; v < 4; ++v) { const int t = s_wsum[v]; s_wpre[v] = run; run += t; }
        s_wpre[4] = run;
    }
    __syncthreads();
    const int total2 = s_wpre[4];
    const int count  = total2 < n ? total2 : n;
    int slot = s_wpre[wave] + incl - s;          // exclusive prefix == rank base

    // Emit own bits to consecutive slots (ascending index == reference order).
    float* const outa = out_pts + (size_t)a * n * 3;
    #pragma unroll
    for (int u = 0; u < WPT; ++u) {
        unsigned int wm = mw[u];
        while (wm) {
            const int b = __ffs(wm) - 1;
            wm &= wm - 1u;
            if (slot < n) {
                const int i = (wbase + u) * 32 + b;
                outa[3 * slot + 0] = pts[3 * i + 0] - cx;
                outa[3 * slot + 1] = pts[3 * i + 1] - cy;
                outa[3 * slot + 2] = pts[3 * i + 2];
            }
            ++slot;
        }
    }

    for (int t = count * 3 + tid; t < n * 3; t += 256) outa[t] = 0.f;
    if (tid == 0) out_cnt[a] = (float)count;
}

// ---- R15 stream-pipeline kernels (fallback if cooperative launch fails) ----

__global__ __launch_bounds__(256) void scatter_kernel(
    const float* __restrict__ pts, int* __restrict__ bincnt,
    float4* __restrict__ bucket, int N)
{
    const int i = blockIdx.x * 256 + threadIdx.x;
    if (i >= N) return;
    const float px = pts[3 * i + 0], py = pts[3 * i + 1], pz = pts[3 * i + 2];
    const float s = NB / 100.0f;
    const int bx = min(NB - 1, (int)(px * s));
    const int by = min(NB - 1, (int)(py * s));
    const int bin = by * NB + bx;
    const int slot = atomicAdd(&bincnt[bin], 1);
    if (slot < CAPB)
        bucket[bin * CAPB + slot] = make_float4(px, py, pz, __int_as_float(i));
}

__global__ __launch_bounds__(512) void anchor_kernel(
    const float* __restrict__ pts, const float* __restrict__ anc,
    const int* __restrict__ bincnt, const float4* __restrict__ bucket,
    float* __restrict__ out_pts, float* __restrict__ out_cnt, int n)
{
    const int a    = blockIdx.x;
    const int tid  = threadIdx.x;
    const int lane = tid & 63;
    const int wave = tid >> 6;

    const float cx = anc[a * 6 + 0], cy = anc[a * 6 + 1];
    const float w  = anc[a * 6 + 3], l  = anc[a * 6 + 4], h = anc[a * 6 + 5];
    const float xl = cx - w * 0.5f, xh = cx + w * 0.5f;
    const float yl = cy - l * 0.5f, yh = cy + l * 0.5f;

    __shared__ unsigned int s_mask[NWRD];
    __shared__ int s_bcnt[MAXBIN];
    __shared__ int s_wsum[8], s_wpre[9];

    #pragma unroll
    for (int u = 0; u < 7; ++u) s_mask[tid + u * 512] = 0u;

    const float sc = NB / 100.0f;
    const int bx0 = max(0, (int)floorf(xl * sc));
    const int bx1 = min(NB - 1, (int)floorf(xh * sc));
    const int by0 = max(0, (int)floorf(yl * sc));
    const int by1 = min(NB - 1, (int)floorf(yh * sc));
    const int nbx = bx1 - bx0 + 1;
    const int nby = by1 - by0 + 1;
    const int nbins = (nbx > 0 && nby > 0) ? nbx * nby : 0;

    for (int t = tid; t < nbins; t += 512) {
        const int by = by0 + t / nbx, bx = bx0 + t % nbx;
        s_bcnt[t] = min(bincnt[by * NB + bx], CAPB);
    }
    __syncthreads();

    const int tot = nbins << 5;
    for (int t = tid; t < tot; t += 512) {
        const int slot = t & (CAPB - 1);
        const int b    = t >> 5;
        if (slot < s_bcnt[b]) {
            const int bin  = (by0 + b / nbx) * NB + bx0 + b % nbx;
            const float4 p = bucket[bin * CAPB + slot];
            if (p.x >= xl && p.x <= xh && p.y >= yl && p.y <= yh &&
                p.z >= 0.0f && p.z <= h) {
                const int idx = __float_as_int(p.w);
                atomicOr(&s_mask[idx >> 5], 1u << (idx & 31));
            }
        }
    }
    __syncthreads();

    const int wbase = tid * 7;
    int s = 0;
    unsigned int mw[7];
    #pragma unroll
    for (int u = 0; u < 7; ++u) {
        mw[u] = s_mask[wbase + u];
        s += __popc(mw[u]);
    }
    int incl = s;
    #pragma unroll
    for (int d = 1; d < 64; d <<= 1) {
        const int t = __shfl_up(incl, d);
        if (lane >= d) incl += t;
    }
    if (lane == 63) s_wsum[wave] = incl;
    __syncthreads();
    if (tid == 0) {
        int run = 0;
        #pragma unroll
        for (int v = 0; v < 8; ++v) { const int t = s_wsum[v]; s_wpre[v] = run; run += t; }
        s_wpre[8] = run;
    }
    __syncthreads();
    const int total = s_wpre[8];
    const int count = total < n ? total : n;
    int slot = s_wpre[wave] + incl - s;

    float* const outa = out_pts + (size_t)a * n * 3;
    #pragma unroll
    for (int u = 0; u < 7; ++u) {
        unsigned int wm = mw[u];
        while (wm) {
            const int b = __ffs(wm) - 1;
            wm &= wm - 1u;
            if (slot < n) {
                const int i = (wbase + u) * 32 + b;
                outa[3 * slot + 0] = pts[3 * i + 0] - cx;
                outa[3 * slot + 1] = pts[3 * i + 1] - cy;
                outa[3 * slot + 2] = pts[3 * i + 2];
            }
            ++slot;
        }
    }
    for (int t = count * 3 + tid; t < n * 3; t += 512) outa[t] = 0.f;
    if (tid == 0) out_cnt[a] = (float)count;
}

// ---- Last-resort fallback (round-1 kernel) ----
__global__ __launch_bounds__(256) void roi_pool_kernel(
    const float* __restrict__ pts, const float* __restrict__ anc,
    float* __restrict__ out_pts, float* __restrict__ out_cnt, int N, int n)
{
    const int a = blockIdx.x;
    const float cx = anc[a * 6 + 0], cy = anc[a * 6 + 1];
    const float w  = anc[a * 6 + 3], l  = anc[a * 6 + 4], h = anc[a * 6 + 5];
    const float xmin = cx - 0.5f * w, xmax = cx + 0.5f * w;
    const float ymin = cy - 0.5f * l, ymax = cy + 0.5f * l;
    const int tid = threadIdx.x, wave = tid >> 6, lane = tid & 63;
    __shared__ int s_tot[4];
    int base = 0;
    float* const outa = out_pts + (size_t)a * n * 3;
    for (int start = 0; start < N; start += 256) {
        const int i = start + tid;
        bool m = false;
        float px = 0.f, py = 0.f, pz = 0.f;
        if (i < N) {
            px = pts[3 * i]; py = pts[3 * i + 1]; pz = pts[3 * i + 2];
            m = (px >= xmin) & (px <= xmax) & (py >= ymin) & (py <= ymax) &
                (pz >= 0.0f) & (pz <= h);
        }
        const unsigned long long ball = __ballot(m);
        const int lanePfx = __popcll(ball & ((1ull << lane) - 1ull));
        if (lane == 0) s_tot[wave] = __popcll(ball);
        __syncthreads();
        const int t0 = s_tot[0], t1 = s_tot[1], t2 = s_tot[2], t3 = s_tot[3];
        int offs = base;
        if (wave > 0) offs += t0;
        if (wave > 1) offs += t1;
        if (wave > 2) offs += t2;
        const int slot = offs + lanePfx;
        if (m && slot < n) {
            float* o = outa + (size_t)slot * 3;
            o[0] = px - cx; o[1] = py - cy; o[2] = pz;
        }
        base += t0 + t1 + t2 + t3;
        __syncthreads();
        if (base >= n) break;
    }
    const int count = base < n ? base : n;
    if (tid == 0) out_cnt[a] = (float)count;
    for (int s = count + tid; s < n; s += 256) {
        float* o = outa + (size_t)s * 3;
        o[0] = 0.f; o[1] = 0.f; o[2] = 0.f;
    }
}

extern "C" void kernel_launch(void* const* d_in, const int* in_sizes, int n_in,
                              void* d_out, int out_size, void* d_ws, size_t ws_size,
                              hipStream_t stream) {
    const float* pts = (const float*)d_in[0];
    const float* anc = (const float*)d_in[1];
    int N = in_sizes[0] / 3;          // 100000
    int A = in_sizes[1] / 6;          // 1024
    int n = (out_size / A - 1) / 3;   // 512

    float* out_pts = (float*)d_out;
    float* out_cnt = (float*)d_out + (size_t)A * n * 3;

    const size_t bucket_bytes = (size_t)NBB * CAPB * sizeof(float4);  // 8 MB
    const size_t cnt_bytes    = (size_t)NBB * sizeof(int);            // 64 KB
    const size_t total_ws     = bucket_bytes + cnt_bytes;

    if (ws_size < total_ws || N > NWRD * 32) {
        roi_pool_kernel<<<dim3(A), dim3(256), 0, stream>>>(pts, anc, out_pts, out_cnt, N, n);
        return;
    }

    float4* bucket = (float4*)d_ws;                        // 16B-aligned base
    int* bincnt    = (int*)((char*)d_ws + bucket_bytes);

    hipError_t cerr = hipErrorUnknown;
    if (A <= 1024 && N <= 1024 * 256 && NBB <= 1024 * 256) {
        void* args[] = {
            (void*)&pts, (void*)&anc, (void*)&bincnt, (void*)&bucket,
            (void*)&out_pts, (void*)&out_cnt, (void*)&N, (void*)&n, (void*)&A
        };
        cerr = hipLaunchCooperativeKernel((void*)fused_kernel, dim3(1024),
                                          dim3(256), args, 0, stream);
    }
    if (cerr != hipSuccess) {
        // Proven R15 stream pipeline.
        hipMemsetAsync(bincnt, 0, cnt_bytes, stream);
        scatter_kernel<<<dim3((N + 255) / 256), dim3(256), 0, stream>>>(
            pts, bincnt, bucket, N);
        anchor_kernel<<<dim3(A), dim3(512), 0, stream>>>(
            pts, anc, bincnt, bucket, out_pts, out_cnt, n);
    }
}

// Round 19
// 79.310 us; speedup vs baseline: 3.1487x; 3.1487x over previous
//
#include <hip/hip_runtime.h>

// ROI point pooling via fixed-capacity spatial buckets. 3 kernels.
// == Best measured configuration (R15, 79.33 us) reverted verbatim. ==
//
// R18 post-mortem pinned the floor: cooperative grid.sync costs ~90 us each
// on this platform (fused_kernel ran 186-192 us with ~12 us of real work,
// VALUBusy 2%) -- fusing the 3 dispatches is strictly worse. Remaining
// budget: ~43 us harness d_ws re-poison (fixed) + ~12 us kernels + ~24 us
// node overhead.
//
// K0 zero:    bincnt[128*128] = 0 (ws is 0xAA-poisoned every call).
// K1 scatter: per point i: bin from (px,py); slot = atomicAdd(bincnt[bin]);
//             bucket[bin][slot] = (px,py,pz, i-as-float).
// K2 anchor:  one 512-thread block per anchor.
//             Phase A: stage the exact window's bin counts into LDS.
//             Phase B: flat scan bins x slots 0..7, unconditional bucket
//               loads (covers ~84% of bins fully; Poisson lambda=6.1).
//             Phase C: guarded scan bins x slots 8..31 (loads only for the
//               ~16% of bins with cnt>8).
//             Hits set bit idx in a 3584-word LDS bitmask (atomicOr,
//             idempotent). Rank = popcount block-scan (7 words/thread, wave
//             shfl-scan + 8-wave combine); each thread emits its own bits to
//             consecutive slots: slot k = #(set bits < idx) == reference
//             cumsum order. Gather pts[idx] ascending; tail zeroed with flat
//             coalesced stores (absorbs the output clear).
//
// Capacity: mean 6.1 pts/bin -> CAPB=32 ~ 10 sigma (no drops).
// Bitmask covers N <= 3584*32 = 114688 (N=100000).

#define NB     128
#define NBB    (NB * NB)
#define CAPB   32
#define NWRD   3584         // 7 words x 512 threads
#define WPT    7
#define MAXBIN 160          // window bins <= 12x12 = 144

__global__ __launch_bounds__(256) void zero_kernel(int* __restrict__ bincnt)
{
    bincnt[blockIdx.x * 256 + threadIdx.x] = 0;
}

__global__ __launch_bounds__(256) void scatter_kernel(
    const float* __restrict__ pts, int* __restrict__ bincnt,
    float4* __restrict__ bucket, int N)
{
    const int i = blockIdx.x * 256 + threadIdx.x;
    if (i >= N) return;
    const float px = pts[3 * i + 0], py = pts[3 * i + 1], pz = pts[3 * i + 2];
    const float s = NB / 100.0f;
    const int bx = min(NB - 1, (int)(px * s));   // px,py >= 0
    const int by = min(NB - 1, (int)(py * s));
    const int bin = by * NB + bx;
    const int slot = atomicAdd(&bincnt[bin], 1);
    if (slot < CAPB)
        bucket[bin * CAPB + slot] = make_float4(px, py, pz, __int_as_float(i));
}

__global__ __launch_bounds__(512) void anchor_kernel(
    const float* __restrict__ pts, const float* __restrict__ anc,
    const int* __restrict__ bincnt, const float4* __restrict__ bucket,
    float* __restrict__ out_pts, float* __restrict__ out_cnt, int n)
{
    const int a    = blockIdx.x;
    const int tid  = threadIdx.x;
    const int lane = tid & 63;
    const int wave = tid >> 6;

    const float cx = anc[a * 6 + 0], cy = anc[a * 6 + 1];
    const float w  = anc[a * 6 + 3], l  = anc[a * 6 + 4], h = anc[a * 6 + 5];
    const float xl = cx - w * 0.5f, xh = cx + w * 0.5f;
    const float yl = cy - l * 0.5f, yh = cy + l * 0.5f;

    __shared__ unsigned int s_mask[NWRD];
    __shared__ int s_bcnt[MAXBIN];
    __shared__ int s_wsum[8], s_wpre[9];

    #pragma unroll
    for (int u = 0; u < WPT; ++u) s_mask[tid + u * 512] = 0u;  // coalesced clear

    const float sc = NB / 100.0f;
    const int bx0 = max(0, (int)floorf(xl * sc));
    const int bx1 = min(NB - 1, (int)floorf(xh * sc));
    const int by0 = max(0, (int)floorf(yl * sc));
    const int by1 = min(NB - 1, (int)floorf(yh * sc));
    const int nbx = bx1 - bx0 + 1;               // <= 12
    const int nby = by1 - by0 + 1;               // <= 12
    const int nbins = (nbx > 0 && nby > 0) ? nbx * nby : 0;

    // Phase A: stage window bin counts.
    for (int t = tid; t < nbins; t += 512) {
        const int by = by0 + t / nbx, bx = bx0 + t % nbx;
        s_bcnt[t] = min(bincnt[by * NB + bx], CAPB);
    }
    __syncthreads();

    // Phase B: slots 0..7, unconditional loads.
    const int totB = nbins * 8;
    for (int t = tid; t < totB; t += 512) {
        const int slot = t & 7;
        const int b    = t >> 3;
        const int cnt  = s_bcnt[b];                            // LDS
        const int bin  = (by0 + b / nbx) * NB + bx0 + b % nbx;
        const float4 p = bucket[bin * CAPB + slot];            // unconditional
        if (slot < cnt &&
            p.x >= xl && p.x <= xh && p.y >= yl && p.y <= yh &&
            p.z >= 0.0f && p.z <= h) {
            const int idx = __float_as_int(p.w);
            atomicOr(&s_mask[idx >> 5], 1u << (idx & 31));
        }
    }

    // Phase C: slots 8..31, guarded (only ~16% of bins have cnt > 8).
    const int totC = nbins * 24;
    for (int t = tid; t < totC; t += 512) {
        const int b    = t / 24;
        const int slot = 8 + t - b * 24;
        const int cnt  = s_bcnt[b];
        if (slot < cnt) {
            const int bin  = (by0 + b / nbx) * NB + bx0 + b % nbx;
            const float4 p = bucket[bin * CAPB + slot];
            if (p.x >= xl && p.x <= xh && p.y >= yl && p.y <= yh &&
                p.z >= 0.0f && p.z <= h) {
                const int idx = __float_as_int(p.w);
                atomicOr(&s_mask[idx >> 5], 1u << (idx & 31));
            }
        }
    }
    __syncthreads();

    // Popcount block-scan: thread owns words [tid*7, tid*7+7).
    const int wbase = tid * WPT;
    int s = 0;
    unsigned int mw[WPT];
    #pragma unroll
    for (int u = 0; u < WPT; ++u) {              // stride-7: conflict-free
        mw[u] = s_mask[wbase + u];
        s += __popc(mw[u]);
    }
    int incl = s;
    #pragma unroll
    for (int d = 1; d < 64; d <<= 1) {
        const int t = __shfl_up(incl, d);
        if (lane >= d) incl += t;
    }
    if (lane == 63) s_wsum[wave] = incl;
    __syncthreads();
    if (tid == 0) {
        int run = 0;
        #pragma unroll
        for (int v = 0; v < 8; ++v) { const int t = s_wsum[v]; s_wpre[v] = run; run += t; }
        s_wpre[8] = run;
    }
    __syncthreads();
    const int total = s_wpre[8];
    const int count = total < n ? total : n;
    int slot = s_wpre[wave] + incl - s;          // exclusive prefix == rank base

    // Emit own bits to consecutive slots (ascending index == reference order).
    float* const outa = out_pts + (size_t)a * n * 3;
    #pragma unroll
    for (int u = 0; u < WPT; ++u) {
        unsigned int wm = mw[u];
        while (wm) {
            const int b = __ffs(wm) - 1;
            wm &= wm - 1u;
            if (slot < n) {
                const int i = (wbase + u) * 32 + b;
                outa[3 * slot + 0] = pts[3 * i + 0] - cx;
                outa[3 * slot + 1] = pts[3 * i + 1] - cy;
                outa[3 * slot + 2] = pts[3 * i + 2];
            }
            ++slot;
        }
    }

    // Flat coalesced tail zero over floats [count*3, n*3).
    for (int t = count * 3 + tid; t < n * 3; t += 512) outa[t] = 0.f;
    if (tid == 0) out_cnt[a] = (float)count;
}

// ---- Fallback (round-1 kernel): ws too small or N > bitmask capacity ----
__global__ __launch_bounds__(256) void roi_pool_kernel(
    const float* __restrict__ pts, const float* __restrict__ anc,
    float* __restrict__ out_pts, float* __restrict__ out_cnt, int N, int n)
{
    const int a = blockIdx.x;
    const float cx = anc[a * 6 + 0], cy = anc[a * 6 + 1];
    const float w  = anc[a * 6 + 3], l  = anc[a * 6 + 4], h = anc[a * 6 + 5];
    const float xmin = cx - 0.5f * w, xmax = cx + 0.5f * w;
    const float ymin = cy - 0.5f * l, ymax = cy + 0.5f * l;
    const int tid = threadIdx.x, wave = tid >> 6, lane = tid & 63;
    __shared__ int s_tot[4];
    int base = 0;
    float* const outa = out_pts + (size_t)a * n * 3;
    for (int start = 0; start < N; start += 256) {
        const int i = start + tid;
        bool m = false;
        float px = 0.f, py = 0.f, pz = 0.f;
        if (i < N) {
            px = pts[3 * i]; py = pts[3 * i + 1]; pz = pts[3 * i + 2];
            m = (px >= xmin) & (px <= xmax) & (py >= ymin) & (py <= ymax) &
                (pz >= 0.0f) & (pz <= h);
        }
        const unsigned long long ball = __ballot(m);
        const int lanePfx = __popcll(ball & ((1ull << lane) - 1ull));
        if (lane == 0) s_tot[wave] = __popcll(ball);
        __syncthreads();
        const int t0 = s_tot[0], t1 = s_tot[1], t2 = s_tot[2], t3 = s_tot[3];
        int offs = base;
        if (wave > 0) offs += t0;
        if (wave > 1) offs += t1;
        if (wave > 2) offs += t2;
        const int slot = offs + lanePfx;
        if (m && slot < n) {
            float* o = outa + (size_t)slot * 3;
            o[0] = px - cx; o[1] = py - cy; o[2] = pz;
        }
        base += t0 + t1 + t2 + t3;
        __syncthreads();
        if (base >= n) break;
    }
    const int count = base < n ? base : n;
    if (tid == 0) out_cnt[a] = (float)count;
    for (int s = count + tid; s < n; s += 256) {
        float* o = outa + (size_t)s * 3;
        o[0] = 0.f; o[1] = 0.f; o[2] = 0.f;
    }
}

extern "C" void kernel_launch(void* const* d_in, const int* in_sizes, int n_in,
                              void* d_out, int out_size, void* d_ws, size_t ws_size,
                              hipStream_t stream) {
    const float* pts = (const float*)d_in[0];
    const float* anc = (const float*)d_in[1];
    const int N = in_sizes[0] / 3;          // 100000
    const int A = in_sizes[1] / 6;          // 1024
    const int n = (out_size / A - 1) / 3;   // 512

    float* out_pts = (float*)d_out;
    float* out_cnt = (float*)d_out + (size_t)A * n * 3;

    const size_t bucket_bytes = (size_t)NBB * CAPB * sizeof(float4);  // 8 MB
    const size_t cnt_bytes    = (size_t)NBB * sizeof(int);            // 64 KB
    const size_t total_ws     = bucket_bytes + cnt_bytes;

    if (ws_size < total_ws || N > NWRD * 32) {
        roi_pool_kernel<<<dim3(A), dim3(256), 0, stream>>>(pts, anc, out_pts, out_cnt, N, n);
        return;
    }

    float4* bucket = (float4*)d_ws;                        // 16B-aligned base
    int* bincnt    = (int*)((char*)d_ws + bucket_bytes);

    const int pb = (N + 255) / 256;                        // 391 point blocks

    zero_kernel<<<dim3(NBB / 256), dim3(256), 0, stream>>>(bincnt);
    scatter_kernel<<<dim3(pb), dim3(256), 0, stream>>>(pts, bincnt, bucket, N);
    anchor_kernel<<<dim3(A), dim3(512), 0, stream>>>(pts, anc, bincnt, bucket,
                                                     out_pts, out_cnt, n);
}